// Round 13
// baseline (189.020 us; speedup 1.0000x reference)
//
#include <hip/hip_runtime.h>
#include <hip/hip_bf16.h>

using short8 = __attribute__((ext_vector_type(8))) short;   // 8 x bf16 bits
using f32x4  = __attribute__((ext_vector_type(4))) float;
using uint4v = __attribute__((ext_vector_type(4))) unsigned;

#if __has_builtin(__builtin_amdgcn_exp2f)
#define EXP2(x) __builtin_amdgcn_exp2f(x)
#else
#define EXP2(x) exp2f(x)
#endif

// Soft workgroup barrier (validated r7): orders LDS via lgkmcnt(0) but
// leaves global register loads in flight across the barrier.
#define SOFT_BARRIER()                                            \
    do {                                                          \
        asm volatile("s_waitcnt lgkmcnt(0)" ::: "memory");        \
        __builtin_amdgcn_s_barrier();                             \
    } while (0)

__device__ __forceinline__ short f2bf(float f) {
    union { float f; unsigned u; } v; v.f = f;
    unsigned r = v.u + 0x7fffu + ((v.u >> 16) & 1u);
    return (short)(r >> 16);
}
// pack two fp32 -> two bf16 (truncation): result = (trunc(b)<<16) | trunc(a)
__device__ __forceinline__ unsigned pack_trunc(float a, float b) {
    union { float f; unsigned u; } ua, ub; ua.f = a; ub.f = b;
#if __has_builtin(__builtin_amdgcn_perm)
    return __builtin_amdgcn_perm(ub.u, ua.u, 0x07060302u);
#else
    return (ub.u & 0xFFFF0000u) | (ua.u >> 16);
#endif
}
__device__ __forceinline__ void async_copy16(const short* g, short* s) {
    __builtin_amdgcn_global_load_lds(
        (const __attribute__((address_space(1))) void*)g,
        (__attribute__((address_space(3))) void*)s, 16, 0, 0);
}

// ---------------------------------------------------------------------------
// fp32 -> bf16 conversion: 5 segments (x, Wq, Wk, Wv, Wo). 4 floats/thread.
// Flat 8192-block grid: blocks 0..4095 -> X (4M elems), then 1024 blocks per
// weight (1M each). All segments divide exactly -> no bounds checks.
// ---------------------------------------------------------------------------
__global__ __launch_bounds__(256) void cvt_f32_bf16(
    const float* __restrict__ s0, const float* __restrict__ s1,
    const float* __restrict__ s2, const float* __restrict__ s3,
    const float* __restrict__ s4,
    short* __restrict__ d0, short* __restrict__ d1, short* __restrict__ d2,
    short* __restrict__ d3, short* __restrict__ d4) {
    const int bid = blockIdx.x;
    const float* s; short* d; int base;
    if (bid < 4096) {
        s = s0; d = d0; base = bid << 10;
    } else {
        const int r = bid - 4096;
        base = (r & 1023) << 10;
        switch (r >> 10) {
            case 0: s = s1; d = d1; break;
            case 1: s = s2; d = d2; break;
            case 2: s = s3; d = d3; break;
            default: s = s4; d = d4; break;
        }
    }
    const int idx = base + threadIdx.x * 4;
    float4 v = *(const float4*)(s + idx);
    short4 o;
    o.x = f2bf(v.x); o.y = f2bf(v.y); o.z = f2bf(v.z); o.w = f2bf(v.w);
    *(short4*)(d + idx) = o;
}

// ---------------------------------------------------------------------------
// GEMM body, 64(M)x128(N) tile, BK=64, 16 K-steps. bf16 in, fp32 accum.
// A[M,K] @ B[N,K]^T. Single LDS buffer + two syncs (r9 proven structure).
//
// Round-13 (r12 post-mortem): r12's 128x64 N-split raised occupancy to 51%
// but DOUBLED A re-reads (FETCH +20MB) and write-amplified C (64-col bf16 =
// 128B lines split across XCDs: WRITE 24.6->59MB) -> net loss. This M-split
// keeps N=128 (A re-reads 8x, C-write lines 256B, per-XCD footprint
// byte-identical to r9: A 2MB + B 1MB/z) while still minting 6 blocks/CU.
// Staging = proven conflict-free patterns (A: 64-row 2-chunk; B: 128-row
// 4-chunk). Fragment reads ((kk*4+quad)^xr): measured zero conflicts.
// bm/bn are parameters (XCD-rectangle decode in the caller).
// MODE 0: bf16 out [M,N], scaled.
// MODE 2: bf16 out TRANSPOSED as VT[b][N][s] (b = row>>11, s = row&2047).
// ---------------------------------------------------------------------------
template <int MODE>
__device__ __forceinline__ void gemm_body(const short* __restrict__ A,
                                          const short* __restrict__ B,
                                          short* __restrict__ C,
                                          float scale,
                                          short* __restrict__ As,
                                          short* __restrict__ Bs,
                                          int bm, int bn) {
    constexpr int Kd = 1024, Nd = 1024, Sd = 2048;

    const int tid  = threadIdx.x;
    const int w    = tid >> 6, lane = tid & 63;
    const int quad = lane >> 4, l16 = lane & 15;
    const int xr   = l16 & 7;
    const int wm   = (w >> 1) * 32, wn = (w & 1) * 64;

    f32x4 acc[2][4];
#pragma unroll
    for (int i = 0; i < 2; ++i)
#pragma unroll
        for (int j = 0; j < 4; ++j) acc[i][j] = (f32x4){0.f, 0.f, 0.f, 0.f};

    for (int k0 = 0; k0 < Kd; k0 += 64) {
        __syncthreads();
#pragma unroll
        for (int c = 0; c < 2; ++c) {           // A: 64 rows x 8 chunks
            int li   = c * 256 + tid;
            int row  = li >> 3;                  // 0..63
            int gcol = ((li & 7) ^ (row & 7)) * 8;
            async_copy16(A + (size_t)(bm + row) * Kd + k0 + gcol, &As[li * 8]);
        }
#pragma unroll
        for (int c = 0; c < 4; ++c) {           // B: 128 rows x 8 chunks
            int li   = c * 256 + tid;
            int row  = li >> 3;                  // 0..127
            int gcol = ((li & 7) ^ (row & 7)) * 8;
            async_copy16(B + (size_t)(bn + row) * Kd + k0 + gcol, &Bs[li * 8]);
        }
        __syncthreads();

#pragma unroll
        for (int kk = 0; kk < 2; ++kk) {
            short8 af[2], bfv[4];
#pragma unroll
            for (int mi = 0; mi < 2; ++mi) {
                const int r = wm + mi * 16 + l16;
                af[mi] = *(const short8*)(
                    &As[r * 64 + (((kk * 4 + quad) ^ xr) * 8)]);
            }
#pragma unroll
            for (int ni = 0; ni < 4; ++ni) {
                const int r = wn + ni * 16 + l16;
                bfv[ni] = *(const short8*)(
                    &Bs[r * 64 + (((kk * 4 + quad) ^ xr) * 8)]);
            }
#pragma unroll
            for (int mi = 0; mi < 2; ++mi)
#pragma unroll
                for (int ni = 0; ni < 4; ++ni) {
                    if constexpr (MODE == 2)
                        acc[mi][ni] = __builtin_amdgcn_mfma_f32_16x16x32_bf16(
                            bfv[ni], af[mi], acc[mi][ni], 0, 0, 0);
                    else
                        acc[mi][ni] = __builtin_amdgcn_mfma_f32_16x16x32_bf16(
                            af[mi], bfv[ni], acc[mi][ni], 0, 0, 0);
                }
        }
    }

    if constexpr (MODE == 2) {
        // D rows (quad*4+r) index B-rows (e dim); D cols (l16) index A-rows (seq)
#pragma unroll
        for (int mi = 0; mi < 2; ++mi) {
            const int m_g = bm + wm + mi * 16 + l16;      // global x-row
            const int b_  = m_g >> 11, s_ = m_g & 2047;
#pragma unroll
            for (int ni = 0; ni < 4; ++ni)
#pragma unroll
                for (int r = 0; r < 4; ++r) {
                    const int n_g = bn + wn + ni * 16 + quad * 4 + r;
                    C[(size_t)b_ * Nd * Sd + (size_t)n_g * Sd + s_] =
                        f2bf(acc[mi][ni][r]);
                }
        }
    } else {
#pragma unroll
        for (int ni = 0; ni < 4; ++ni) {
            const int colg = bn + wn + ni * 16 + l16;
#pragma unroll
            for (int mi = 0; mi < 2; ++mi)
#pragma unroll
                for (int r = 0; r < 4; ++r) {
                    const int rowg = bm + wm + mi * 16 + quad * 4 + r;
                    C[(size_t)rowg * Nd + colg] = f2bf(acc[mi][ni][r] * scale);
                }
        }
    }
}

// csc = d^-0.5 * log2(e), folded into Q so attn does exp2(S) directly
#define CSC 0.18033688f

// ---------------------------------------------------------------------------
// proj_gemm, 1D grid 1536 (64M x 128N tiles): 6 blocks/CU. LDS 24 KB.
// XCD-rectangle decode with the SAME per-XCD footprint as r9's winning
// config: (xcd>>1) owns 16 M-tiles of 64 (= 1024 rows, A 2 MB), (xcd&1)
// owns 4 N-tiles of 128 (= 512 cols, B 1 MB per z). Bijective:
// bid = ((z*64 + r64) << 3) | xcd.
// ---------------------------------------------------------------------------
__global__ __launch_bounds__(256, 6) void proj_gemm(
    const short* __restrict__ X,
    const short* __restrict__ Wq, const short* __restrict__ Wk,
    const short* __restrict__ Wv,
    short* __restrict__ Qo, short* __restrict__ Ko, short* __restrict__ VTo) {
    __shared__ __align__(16) short As[64 * 64];    // 8 KB, shared by all
    __shared__ __align__(16) short Bs[128 * 64];   // 16 KB, instantiations

    const int bid = blockIdx.x;
    const int xcd = bid & 7, idx = bid >> 3;       // idx 0..191
    const int z   = idx >> 6;                      // 0..2
    const int r64 = idx & 63;
    const int bm  = (((xcd >> 1) << 4) + (r64 >> 2)) * 64;   // 64 M-tiles
    const int bn  = (((xcd & 1) << 2) + (r64 & 3)) * 128;    // 8 N-tiles

    if (z == 0)
        gemm_body<0>(X, Wq, Qo, CSC, As, Bs, bm, bn);
    else if (z == 1)
        gemm_body<0>(X, Wk, Ko, 1.0f, As, Bs, bm, bn);
    else
        gemm_body<2>(X, Wv, VTo, 1.0f, As, Bs, bm, bn);
}

// ---------------------------------------------------------------------------
// out_gemm: C[4096,1024] fp32 = A @ W^T + bias. 64(M)x128(N) tiles, BK=64.
// 1D grid 512 (2/CU), XCD-rectangle decode. r9 EXACT structure (best
// measured total): global_load_lds, single LDS buffer, two syncs per step.
// ---------------------------------------------------------------------------
__global__ __launch_bounds__(256, 2) void out_gemm(
    const short* __restrict__ A, const short* __restrict__ B,
    const float* __restrict__ bias, float* __restrict__ C) {
    constexpr int Kd = 1024, Nd = 1024;
    __shared__ __align__(16) short As[64 * 64];
    __shared__ __align__(16) short Bs[128 * 64];

    const int tid  = threadIdx.x;
    const int w    = tid >> 6, lane = tid & 63;
    const int quad = lane >> 4, l16 = lane & 15;
    const int xr   = l16 & 7;
    const int wm   = (w >> 1) * 32, wn = (w & 1) * 64;

    const int bid = blockIdx.x;
    const int xcd = bid & 7, idx = bid >> 3;       // idx 0..63
    const int bm  = (((xcd >> 1) << 4) + (idx >> 2)) * 64;   // 64 M-tiles
    const int bn  = (((xcd & 1) << 2) + (idx & 3)) * 128;    // 8 N-tiles

    f32x4 acc[2][4];
#pragma unroll
    for (int i = 0; i < 2; ++i)
#pragma unroll
        for (int j = 0; j < 4; ++j) acc[i][j] = (f32x4){0.f, 0.f, 0.f, 0.f};

    for (int k0 = 0; k0 < Kd; k0 += 64) {
        __syncthreads();
#pragma unroll
        for (int c = 0; c < 2; ++c) {
            int li   = c * 256 + tid;
            int row  = li >> 3;                    // 0..63
            int gcol = ((li & 7) ^ (row & 7)) * 8;
            async_copy16(A + (size_t)(bm + row) * Kd + k0 + gcol, &As[li * 8]);
        }
#pragma unroll
        for (int c = 0; c < 4; ++c) {
            int li   = c * 256 + tid;
            int row  = li >> 3;                    // 0..127
            int gcol = ((li & 7) ^ (row & 7)) * 8;
            async_copy16(B + (size_t)(bn + row) * Kd + k0 + gcol, &Bs[li * 8]);
        }
        __syncthreads();

#pragma unroll
        for (int kk = 0; kk < 2; ++kk) {
            short8 af[2], bfv[4];
#pragma unroll
            for (int mi = 0; mi < 2; ++mi) {
                const int r = wm + mi * 16 + l16;
                af[mi] = *(const short8*)(
                    &As[r * 64 + (((kk * 4 + quad) ^ xr) * 8)]);
            }
#pragma unroll
            for (int ni = 0; ni < 4; ++ni) {
                const int r = wn + ni * 16 + l16;
                bfv[ni] = *(const short8*)(
                    &Bs[r * 64 + (((kk * 4 + quad) ^ xr) * 8)]);
            }
#pragma unroll
            for (int mi = 0; mi < 2; ++mi)
#pragma unroll
                for (int ni = 0; ni < 4; ++ni)
                    acc[mi][ni] = __builtin_amdgcn_mfma_f32_16x16x32_bf16(
                        af[mi], bfv[ni], acc[mi][ni], 0, 0, 0);
        }
    }

#pragma unroll
    for (int ni = 0; ni < 4; ++ni) {
        const int colg = bn + wn + ni * 16 + l16;
        const float bv = bias[colg];
#pragma unroll
        for (int mi = 0; mi < 2; ++mi)
#pragma unroll
            for (int r = 0; r < 4; ++r) {
                const int rowg = bm + wm + mi * 16 + quad * 4 + r;
                C[(size_t)rowg * Nd + colg] = acc[mi][ni][r] + bv;
            }
    }
}

// ---------------------------------------------------------------------------
// Flash attention, no-max softmax. (unchanged from round 7 — control)
// Q pre-scaled by CSC. Q/K: [b*s, e] bf16.  VT: [b][e][s] bf16.
// 128 q/block, 32 q/wave, 4 waves (2 waves/SIMD), KV=64.
// Dual-tile ILP pipeline: PV(t-1) interleaved with QK(t); P in two named
// reg sets; V triple-buffered, K double-buffered; ONE soft barrier/tile.
// ---------------------------------------------------------------------------
__global__ __launch_bounds__(256, 2) void attn_kernel(
    const short* __restrict__ Q, const short* __restrict__ K,
    const short* __restrict__ VT, short* __restrict__ O) {
    constexpr int S = 2048, E = 1024, NT = S / 64;   // 32 tiles of 64 keys
    __shared__ __align__(16) short Ks[2][64 * 64];
    __shared__ __align__(16) short Vs[3][64 * 64];

    const int tid  = threadIdx.x;
    const int w    = tid >> 6, lane = tid & 63;
    const int quad = lane >> 4, l16 = lane & 15;

    // XCD-locality decode (round-robin model: XCD = linear_bid & 7)
    const int bid  = blockIdx.x;
    const int xcd  = bid & 7, slot = bid >> 3;
    const int qt   = slot & 15;
    const int bh   = xcd + ((slot >> 4) << 3);
    const int b    = bh >> 4, h = bh & 15;

    const int    q0   = qt * 128 + w * 32;
    const size_t base = (size_t)b * S * E;
    const size_t vtb  = (size_t)b * E * S;
    const int    hc   = h * 64;
    const int    xr   = l16 & 7;

    // Q fragments (B-operand: n=query=l16, k=dim=quad*8+j), 2 query groups
    short8 aq[2][2];
#pragma unroll
    for (int qg = 0; qg < 2; ++qg) {
        const short* qp = Q + base + (size_t)(q0 + qg * 16 + l16) * E + hc + quad * 8;
        aq[qg][0] = *(const short8*)(qp);
        aq[qg][1] = *(const short8*)(qp + 32);
    }

    f32x4 oT[2][4], o_sum[2];
#pragma unroll
    for (int qg = 0; qg < 2; ++qg) {
        o_sum[qg] = (f32x4){0.f, 0.f, 0.f, 0.f};
#pragma unroll
        for (int i = 0; i < 4; ++i) oT[qg][i] = (f32x4){0.f, 0.f, 0.f, 0.f};
    }

    // staging: li = c*256+tid -> row=li>>3 (0..63), cc=li&7 (16B chunk).
    // K: xor-swizzled chunks. V: permuted key order, split into two b64.
    int          kdst[2], vdst0[2], vdst1[2];
    const short* kga[2];
    const short* vga[2];
#pragma unroll
    for (int c = 0; c < 2; ++c) {
        int li = c * 256 + tid, row = li >> 3, cc = li & 7;
        kdst[c] = row * 64 + ((cc ^ (row & 7)) * 8);
        int c0   = 4 * (cc >> 2) + 2 * (cc & 1);   // phys chunk of keys cc*8..+3
        int boff = 4 * ((cc >> 1) & 1);            // within-chunk half
        vdst0[c] = row * 64 + ((c0 ^ (row & 7)) * 8) + boff;
        vdst1[c] = row * 64 + (((c0 + 1) ^ (row & 7)) * 8) + boff;
        kga[c]   = K + base + (size_t)row * E + hc + cc * 8;
        vga[c]   = VT + vtb + (size_t)(hc + row) * S + cc * 8;
    }

    short8 kr[2], vr[2];
    auto load_regs = [&](int t) {
#pragma unroll
        for (int c = 0; c < 2; ++c) {
            kr[c] = *(const short8*)(kga[c] + (size_t)t * 64 * E);
            vr[c] = *(const short8*)(vga[c] + t * 64);
        }
    };
    auto store_regs = [&](short* Kn, short* Vn) {
#pragma unroll
        for (int c = 0; c < 2; ++c) {
            *(short8*)(&Kn[kdst[c]]) = kr[c];
            short4 lo, hi;
            lo.x = vr[c][0]; lo.y = vr[c][1]; lo.z = vr[c][2]; lo.w = vr[c][3];
            hi.x = vr[c][4]; hi.y = vr[c][5]; hi.z = vr[c][6]; hi.w = vr[c][7];
            *(short4*)(&Vn[vdst0[c]]) = lo;
            *(short4*)(&Vn[vdst1[c]]) = hi;
        }
    };

    const short8 ones = (short8){0x3F80, 0x3F80, 0x3F80, 0x3F80,
                                 0x3F80, 0x3F80, 0x3F80, 0x3F80};
    const float  LB   = 0.00281502f;   // log2(1 + 2^-9): centers P truncation

    uint4v pkvA[2][2], pkvB[2][2];   // [qg][ks] two P-state sets (prev/cur)

    // QK half h (kn = 2h, 2h+1): writes pc[*][h]
    auto qk_half = [&](const short* Kc, uint4v (&pc)[2][2], int h) {
#pragma unroll
        for (int kh = 0; kh < 2; ++kh) {
            const int    kn  = h * 2 + kh;
            const short* kb  = &Kc[(kn * 16 + l16) * 64];
            short8       bk0 = *(const short8*)(kb + ((quad ^ xr) * 8));
            short8       bk1 = *(const short8*)(kb + (((quad + 4) ^ xr) * 8));
#pragma unroll
            for (int qg = 0; qg < 2; ++qg) {
                f32x4 a = (f32x4){LB, LB, LB, LB};
                a = __builtin_amdgcn_mfma_f32_16x16x32_bf16(bk0, aq[qg][0], a, 0, 0, 0);
                a = __builtin_amdgcn_mfma_f32_16x16x32_bf16(bk1, aq[qg][1], a, 0, 0, 0);
                pc[qg][h][kh * 2]     = pack_trunc(EXP2(a[0]), EXP2(a[1]));
                pc[qg][h][kh * 2 + 1] = pack_trunc(EXP2(a[2]), EXP2(a[3]));
            }
        }
    };
    // PV slice ks: consumes pp[*][ks]
    auto pv_half = [&](const short* Vp, uint4v (&pp)[2][2], int ks) {
        short8 pf[2];
#pragma unroll
        for (int qg = 0; qg < 2; ++qg) {
            union { uint4v u; short8 s; } cv;
            cv.u   = pp[qg][ks];
            pf[qg] = cv.s;
            o_sum[qg] = __builtin_amdgcn_mfma_f32_16x16x32_bf16(
                ones, pf[qg], o_sum[qg], 0, 0, 0);
        }
#pragma unroll
        for (int ni = 0; ni < 4; ++ni) {
            const int rv = ni * 16 + l16;
            short8 vb =
                *(const short8*)(&Vp[rv * 64 + (((ks * 4 + quad) ^ xr) * 8)]);
#pragma unroll
            for (int qg = 0; qg < 2; ++qg)
                oT[qg][ni] = __builtin_amdgcn_mfma_f32_16x16x32_bf16(
                    vb, pf[qg], oT[qg][ni], 0, 0, 0);
        }
    };

    // one steady-state iteration: PV(kt-1) interleaved with QK(kt)
    auto body = [&](int kt, uint4v (&pp)[2][2], uint4v (&pc)[2][2]) {
        if (kt + 1 < NT) {
            store_regs(Ks[(kt + 1) & 1], Vs[(kt + 1) % 3]);
            if (kt + 2 < NT) load_regs(kt + 2);
        }
        const short* Kc = Ks[kt & 1];
        const short* Vp = Vs[(kt - 1) % 3];
        __builtin_amdgcn_s_setprio(1);
        pv_half(Vp, pp, 0);
        qk_half(Kc, pc, 0);
        pv_half(Vp, pp, 1);
        qk_half(Kc, pc, 1);
        __builtin_amdgcn_s_setprio(0);
        SOFT_BARRIER();
    };

    // prologue: t0 -> regs -> buf0; t1 -> regs
    load_regs(0);
    store_regs(Ks[0], Vs[0]);
    load_regs(1);
    SOFT_BARRIER();
    // body0: store tile1, prefetch tile2, QK(0) -> pkvA
    store_regs(Ks[1], Vs[1]);
    load_regs(2);
    __builtin_amdgcn_s_setprio(1);
    qk_half(Ks[0], pkvA, 0);
    qk_half(Ks[0], pkvA, 1);
    __builtin_amdgcn_s_setprio(0);
    SOFT_BARRIER();

    // steady state: bodies kt = 1..30 in pairs (static A/B roles), then 31
#pragma unroll 1
    for (int kt = 1; kt < NT - 1; kt += 2) {
        body(kt, pkvA, pkvB);
        body(kt + 1, pkvB, pkvA);
    }
    body(NT - 1, pkvA, pkvB);
    // epilogue PV: tile NT-1 from pkvB, V in Vs[(NT-1)%3]
    __builtin_amdgcn_s_setprio(1);
    pv_half(Vs[(NT - 1) % 3], pkvB, 0);
    pv_half(Vs[(NT - 1) % 3], pkvB, 1);
    __builtin_amdgcn_s_setprio(0);

    // epilogue: O^T C-layout: col=query=l16, row=dim=ni*16+quad*4+r
#pragma unroll
    for (int qg = 0; qg < 2; ++qg) {
        const float inv = 1.0f / o_sum[qg][0];
        const int   qg_ = q0 + qg * 16 + l16;
#pragma unroll
        for (int ni = 0; ni < 4; ++ni) {
            short4 ov;
            ov.x = f2bf(oT[qg][ni][0] * inv);
            ov.y = f2bf(oT[qg][ni][1] * inv);
            ov.z = f2bf(oT[qg][ni][2] * inv);
            ov.w = f2bf(oT[qg][ni][3] * inv);
            *(short4*)(&O[base + (size_t)qg_ * E + hc + ni * 16 + quad * 4]) = ov;
        }
    }
}

// ---------------------------------------------------------------------------
extern "C" void kernel_launch(void* const* d_in, const int* in_sizes, int n_in,
                              void* d_out, int out_size, void* d_ws, size_t ws_size,
                              hipStream_t stream) {
    const float* x  = (const float*)d_in[0];
    const float* Wq = (const float*)d_in[1];
    const float* Wk = (const float*)d_in[2];
    const float* Wv = (const float*)d_in[3];
    const float* Wo = (const float*)d_in[4];
    const float* bo = (const float*)d_in[5];
    float* out = (float*)d_out;

    constexpr int XN = 2 * 2048 * 1024;   // 4M elements
    constexpr int WN = 1024 * 1024;       // 1M elements

    short* Xb  = (short*)d_ws;     // 4M shorts; reused as attention-out buffer
    short* Wqb = Xb + XN;
    short* Wkb = Wqb + WN;
    short* Wvb = Wkb + WN;
    short* Wob = Wvb + WN;
    short* Qb  = Wob + WN;
    short* Kb  = Qb + XN;
    short* VTb = Kb + XN;          // [b][e][s]

    cvt_f32_bf16<<<dim3(8192), 256, 0, stream>>>(
        x, Wq, Wk, Wv, Wo, Xb, Wqb, Wkb, Wvb, Wob);
    proj_gemm<<<dim3(1536), 256, 0, stream>>>(Xb, Wqb, Wkb, Wvb, Qb, Kb, VTb);
    attn_kernel<<<dim3(512), 256, 0, stream>>>(Qb, Kb, VTb, Xb /*O*/);
    out_gemm<<<dim3(512), 256, 0, stream>>>(Xb, Wob, bo, out);
}

// Round 14
// 161.120 us; speedup vs baseline: 1.1732x; 1.1732x over previous
//
#include <hip/hip_runtime.h>
#include <hip/hip_bf16.h>

using short8 = __attribute__((ext_vector_type(8))) short;   // 8 x bf16 bits
using f32x4  = __attribute__((ext_vector_type(4))) float;
using uint4v = __attribute__((ext_vector_type(4))) unsigned;

#if __has_builtin(__builtin_amdgcn_exp2f)
#define EXP2(x) __builtin_amdgcn_exp2f(x)
#else
#define EXP2(x) exp2f(x)
#endif

// Soft workgroup barrier (validated r7): orders LDS via lgkmcnt(0) but
// leaves global register loads in flight across the barrier.
#define SOFT_BARRIER()                                            \
    do {                                                          \
        asm volatile("s_waitcnt lgkmcnt(0)" ::: "memory");        \
        __builtin_amdgcn_s_barrier();                             \
    } while (0)

__device__ __forceinline__ short f2bf(float f) {
    union { float f; unsigned u; } v; v.f = f;
    unsigned r = v.u + 0x7fffu + ((v.u >> 16) & 1u);
    return (short)(r >> 16);
}
// pack two fp32 -> two bf16 (truncation): result = (trunc(b)<<16) | trunc(a)
__device__ __forceinline__ unsigned pack_trunc(float a, float b) {
    union { float f; unsigned u; } ua, ub; ua.f = a; ub.f = b;
#if __has_builtin(__builtin_amdgcn_perm)
    return __builtin_amdgcn_perm(ub.u, ua.u, 0x07060302u);
#else
    return (ub.u & 0xFFFF0000u) | (ua.u >> 16);
#endif
}
__device__ __forceinline__ void async_copy16(const short* g, short* s) {
    __builtin_amdgcn_global_load_lds(
        (const __attribute__((address_space(1))) void*)g,
        (__attribute__((address_space(3))) void*)s, 16, 0, 0);
}

// ---------------------------------------------------------------------------
// fp32 -> bf16 conversion: 5 segments (x, Wq, Wk, Wv, Wo). 4 floats/thread.
// Flat 8192-block grid: blocks 0..4095 -> X (4M elems), then 1024 blocks per
// weight (1M each). All segments divide exactly -> no bounds checks.
// ---------------------------------------------------------------------------
__global__ __launch_bounds__(256) void cvt_f32_bf16(
    const float* __restrict__ s0, const float* __restrict__ s1,
    const float* __restrict__ s2, const float* __restrict__ s3,
    const float* __restrict__ s4,
    short* __restrict__ d0, short* __restrict__ d1, short* __restrict__ d2,
    short* __restrict__ d3, short* __restrict__ d4) {
    const int bid = blockIdx.x;
    const float* s; short* d; int base;
    if (bid < 4096) {
        s = s0; d = d0; base = bid << 10;
    } else {
        const int r = bid - 4096;
        base = (r & 1023) << 10;
        switch (r >> 10) {
            case 0: s = s1; d = d1; break;
            case 1: s = s2; d = d2; break;
            case 2: s = s3; d = d3; break;
            default: s = s4; d = d4; break;
        }
    }
    const int idx = base + threadIdx.x * 4;
    float4 v = *(const float4*)(s + idx);
    short4 o;
    o.x = f2bf(v.x); o.y = f2bf(v.y); o.z = f2bf(v.z); o.w = f2bf(v.w);
    *(short4*)(d + idx) = o;
}

// ---------------------------------------------------------------------------
// GEMM body (r9 proven-best structure). bf16 in, fp32 accum.
// A[M,K] @ B[N,K]^T. 128x128 tile, BK=64. global_load_lds staging, single
// LDS buffer, two syncs per K-step. Global-side xor swizzle; fragment reads
// ((kk*4+quad)^xr): measured conflict-free. bm/bn are parameters
// (XCD-rectangle decode in the caller — the r9 win).
//
// Tile-shape ledger (measured): 128x128 = best. 128x64 (r12): Q/K row
// writes shrink to 128 B partial lines -> WRITE 24.6->59 MB RMW, FETCH +20
// MB (A re-reads 2x). 64x128 (r13): VT s-segments shrink to 128 B -> WRITE
// ~56 MB RMW, FETCH ~63 MB. Occupancy-via-dbuf (r10): costs the 3rd
// block/CU, -8 us. proj occupancy levers are CLOSED on all three routes.
// MODE 0: bf16 out [M,N], scaled.
// MODE 2: bf16 out TRANSPOSED as VT[b][N][s] (b = row>>11, s = row&2047).
// ---------------------------------------------------------------------------
template <int MODE>
__device__ __forceinline__ void gemm_body(const short* __restrict__ A,
                                          const short* __restrict__ B,
                                          short* __restrict__ C,
                                          float scale,
                                          short* __restrict__ As,
                                          short* __restrict__ Bs,
                                          int bm, int bn) {
    constexpr int Kd = 1024, Nd = 1024, Sd = 2048;

    const int tid  = threadIdx.x;
    const int w    = tid >> 6, lane = tid & 63;
    const int quad = lane >> 4, l16 = lane & 15;
    const int xr   = l16 & 7;
    const int wm   = (w >> 1) * 64, wn = (w & 1) * 64;

    f32x4 acc[4][4];
#pragma unroll
    for (int i = 0; i < 4; ++i)
#pragma unroll
        for (int j = 0; j < 4; ++j) acc[i][j] = (f32x4){0.f, 0.f, 0.f, 0.f};

    for (int k0 = 0; k0 < Kd; k0 += 64) {
        __syncthreads();
#pragma unroll
        for (int c = 0; c < 4; ++c) {
            int li   = c * 256 + tid;
            int row  = li >> 3;                    // 0..127
            int gcol = ((li & 7) ^ (row & 7)) * 8; // permuted global chunk
            async_copy16(A + (size_t)(bm + row) * Kd + k0 + gcol, &As[li * 8]);
            async_copy16(B + (size_t)(bn + row) * Kd + k0 + gcol, &Bs[li * 8]);
        }
        __syncthreads();

#pragma unroll
        for (int kk = 0; kk < 2; ++kk) {
            short8 af[4], bfv[4];
#pragma unroll
            for (int mi = 0; mi < 4; ++mi) {
                const int r = wm + mi * 16 + l16;
                af[mi] = *(const short8*)(
                    &As[r * 64 + (((kk * 4 + quad) ^ xr) * 8)]);
            }
#pragma unroll
            for (int ni = 0; ni < 4; ++ni) {
                const int r = wn + ni * 16 + l16;
                bfv[ni] = *(const short8*)(
                    &Bs[r * 64 + (((kk * 4 + quad) ^ xr) * 8)]);
            }
#pragma unroll
            for (int mi = 0; mi < 4; ++mi)
#pragma unroll
                for (int ni = 0; ni < 4; ++ni) {
                    if constexpr (MODE == 2)
                        acc[mi][ni] = __builtin_amdgcn_mfma_f32_16x16x32_bf16(
                            bfv[ni], af[mi], acc[mi][ni], 0, 0, 0);
                    else
                        acc[mi][ni] = __builtin_amdgcn_mfma_f32_16x16x32_bf16(
                            af[mi], bfv[ni], acc[mi][ni], 0, 0, 0);
                }
        }
    }

    if constexpr (MODE == 2) {
        // D rows (quad*4+r) index B-rows (e dim); D cols (l16) index A-rows (seq)
#pragma unroll
        for (int mi = 0; mi < 4; ++mi) {
            const int m_g = bm + wm + mi * 16 + l16;      // global x-row
            const int b_  = m_g >> 11, s_ = m_g & 2047;
#pragma unroll
            for (int ni = 0; ni < 4; ++ni)
#pragma unroll
                for (int r = 0; r < 4; ++r) {
                    const int n_g = bn + wn + ni * 16 + quad * 4 + r;
                    C[(size_t)b_ * Nd * Sd + (size_t)n_g * Sd + s_] =
                        f2bf(acc[mi][ni][r]);
                }
        }
    } else {
#pragma unroll
        for (int ni = 0; ni < 4; ++ni) {
            const int colg = bn + wn + ni * 16 + l16;
#pragma unroll
            for (int mi = 0; mi < 4; ++mi)
#pragma unroll
                for (int r = 0; r < 4; ++r) {
                    const int rowg = bm + wm + mi * 16 + quad * 4 + r;
                    C[(size_t)rowg * Nd + colg] = f2bf(acc[mi][ni][r] * scale);
                }
        }
    }
}

// csc = d^-0.5 * log2(e), folded into Q so attn does exp2(S) directly
#define CSC 0.18033688f

// ---------------------------------------------------------------------------
// proj_gemm, 1D grid 768 (r9 exact: 32 KB LDS, 3 blocks/CU, full residency).
// XCD-rectangle decode: XCD c owns an 8bm x 4bn rectangle for all 3 z.
// ---------------------------------------------------------------------------
__global__ __launch_bounds__(256, 3) void proj_gemm(
    const short* __restrict__ X,
    const short* __restrict__ Wq, const short* __restrict__ Wk,
    const short* __restrict__ Wv,
    short* __restrict__ Qo, short* __restrict__ Ko, short* __restrict__ VTo) {
    __shared__ __align__(16) short As[128 * 64];   // single allocation shared
    __shared__ __align__(16) short Bs[128 * 64];   // by all instantiations

    const int bid = blockIdx.x;
    const int xcd = bid & 7, idx = bid >> 3;       // idx 0..95
    const int z   = idx >> 5;                      // 0..2
    const int rem = idx & 31;
    const int bm  = (((xcd >> 1) * 8) + (rem >> 2)) * 128;   // 32 M-tiles
    const int bn  = (((xcd & 1) * 4) + (rem & 3)) * 128;     // 8 N-tiles

    if (z == 0)
        gemm_body<0>(X, Wq, Qo, CSC, As, Bs, bm, bn);
    else if (z == 1)
        gemm_body<0>(X, Wk, Ko, 1.0f, As, Bs, bm, bn);
    else
        gemm_body<2>(X, Wv, VTo, 1.0f, As, Bs, bm, bn);
}

// ---------------------------------------------------------------------------
// out_gemm: C[4096,1024] fp32 = A @ W^T + bias. 64(M)x128(N) tiles, BK=64.
// 1D grid 512 (2/CU), XCD-rectangle decode. r9 exact structure:
// global_load_lds, single LDS buffer, two syncs per step.
// ---------------------------------------------------------------------------
__global__ __launch_bounds__(256, 2) void out_gemm(
    const short* __restrict__ A, const short* __restrict__ B,
    const float* __restrict__ bias, float* __restrict__ C) {
    constexpr int Kd = 1024, Nd = 1024;
    __shared__ __align__(16) short As[64 * 64];
    __shared__ __align__(16) short Bs[128 * 64];

    const int tid  = threadIdx.x;
    const int w    = tid >> 6, lane = tid & 63;
    const int quad = lane >> 4, l16 = lane & 15;
    const int xr   = l16 & 7;
    const int wm   = (w >> 1) * 32, wn = (w & 1) * 64;

    const int bid = blockIdx.x;
    const int xcd = bid & 7, idx = bid >> 3;       // idx 0..63
    const int bm  = (((xcd >> 1) * 16) + (idx >> 2)) * 64;   // 64 M-tiles
    const int bn  = (((xcd & 1) * 4) + (idx & 3)) * 128;     // 8 N-tiles

    f32x4 acc[2][4];
#pragma unroll
    for (int i = 0; i < 2; ++i)
#pragma unroll
        for (int j = 0; j < 4; ++j) acc[i][j] = (f32x4){0.f, 0.f, 0.f, 0.f};

    for (int k0 = 0; k0 < Kd; k0 += 64) {
        __syncthreads();
#pragma unroll
        for (int c = 0; c < 2; ++c) {
            int li   = c * 256 + tid;
            int row  = li >> 3;                    // 0..63
            int gcol = ((li & 7) ^ (row & 7)) * 8;
            async_copy16(A + (size_t)(bm + row) * Kd + k0 + gcol, &As[li * 8]);
        }
#pragma unroll
        for (int c = 0; c < 4; ++c) {
            int li   = c * 256 + tid;
            int row  = li >> 3;                    // 0..127
            int gcol = ((li & 7) ^ (row & 7)) * 8;
            async_copy16(B + (size_t)(bn + row) * Kd + k0 + gcol, &Bs[li * 8]);
        }
        __syncthreads();

#pragma unroll
        for (int kk = 0; kk < 2; ++kk) {
            short8 af[2], bfv[4];
#pragma unroll
            for (int mi = 0; mi < 2; ++mi) {
                const int r = wm + mi * 16 + l16;
                af[mi] = *(const short8*)(
                    &As[r * 64 + (((kk * 4 + quad) ^ xr) * 8)]);
            }
#pragma unroll
            for (int ni = 0; ni < 4; ++ni) {
                const int r = wn + ni * 16 + l16;
                bfv[ni] = *(const short8*)(
                    &Bs[r * 64 + (((kk * 4 + quad) ^ xr) * 8)]);
            }
#pragma unroll
            for (int mi = 0; mi < 2; ++mi)
#pragma unroll
                for (int ni = 0; ni < 4; ++ni)
                    acc[mi][ni] = __builtin_amdgcn_mfma_f32_16x16x32_bf16(
                        af[mi], bfv[ni], acc[mi][ni], 0, 0, 0);
        }
    }

#pragma unroll
    for (int ni = 0; ni < 4; ++ni) {
        const int colg = bn + wn + ni * 16 + l16;
        const float bv = bias[colg];
#pragma unroll
        for (int mi = 0; mi < 2; ++mi)
#pragma unroll
            for (int r = 0; r < 4; ++r) {
                const int rowg = bm + wm + mi * 16 + quad * 4 + r;
                C[(size_t)rowg * Nd + colg] = acc[mi][ni][r] + bv;
            }
    }
}

// ---------------------------------------------------------------------------
// Flash attention, no-max softmax. (r7 structure — session best)
// Q pre-scaled by CSC. Q/K: [b*s, e] bf16.  VT: [b][e][s] bf16.
// 128 q/block, 32 q/wave, 4 waves (2 waves/SIMD), KV=64.
// Dual-tile ILP pipeline: PV(t-1) interleaved with QK(t); P in two named
// reg sets; V triple-buffered, K double-buffered; ONE soft barrier/tile.
// ---------------------------------------------------------------------------
__global__ __launch_bounds__(256, 2) void attn_kernel(
    const short* __restrict__ Q, const short* __restrict__ K,
    const short* __restrict__ VT, short* __restrict__ O) {
    constexpr int S = 2048, E = 1024, NT = S / 64;   // 32 tiles of 64 keys
    __shared__ __align__(16) short Ks[2][64 * 64];
    __shared__ __align__(16) short Vs[3][64 * 64];

    const int tid  = threadIdx.x;
    const int w    = tid >> 6, lane = tid & 63;
    const int quad = lane >> 4, l16 = lane & 15;

    // XCD-locality decode (round-robin model: XCD = linear_bid & 7)
    const int bid  = blockIdx.x;
    const int xcd  = bid & 7, slot = bid >> 3;
    const int qt   = slot & 15;
    const int bh   = xcd + ((slot >> 4) << 3);
    const int b    = bh >> 4, h = bh & 15;

    const int    q0   = qt * 128 + w * 32;
    const size_t base = (size_t)b * S * E;
    const size_t vtb  = (size_t)b * E * S;
    const int    hc   = h * 64;
    const int    xr   = l16 & 7;

    // Q fragments (B-operand: n=query=l16, k=dim=quad*8+j), 2 query groups
    short8 aq[2][2];
#pragma unroll
    for (int qg = 0; qg < 2; ++qg) {
        const short* qp = Q + base + (size_t)(q0 + qg * 16 + l16) * E + hc + quad * 8;
        aq[qg][0] = *(const short8*)(qp);
        aq[qg][1] = *(const short8*)(qp + 32);
    }

    f32x4 oT[2][4], o_sum[2];
#pragma unroll
    for (int qg = 0; qg < 2; ++qg) {
        o_sum[qg] = (f32x4){0.f, 0.f, 0.f, 0.f};
#pragma unroll
        for (int i = 0; i < 4; ++i) oT[qg][i] = (f32x4){0.f, 0.f, 0.f, 0.f};
    }

    // staging: li = c*256+tid -> row=li>>3 (0..63), cc=li&7 (16B chunk).
    // K: xor-swizzled chunks. V: permuted key order, split into two b64.
    int          kdst[2], vdst0[2], vdst1[2];
    const short* kga[2];
    const short* vga[2];
#pragma unroll
    for (int c = 0; c < 2; ++c) {
        int li = c * 256 + tid, row = li >> 3, cc = li & 7;
        kdst[c] = row * 64 + ((cc ^ (row & 7)) * 8);
        int c0   = 4 * (cc >> 2) + 2 * (cc & 1);   // phys chunk of keys cc*8..+3
        int boff = 4 * ((cc >> 1) & 1);            // within-chunk half
        vdst0[c] = row * 64 + ((c0 ^ (row & 7)) * 8) + boff;
        vdst1[c] = row * 64 + (((c0 + 1) ^ (row & 7)) * 8) + boff;
        kga[c]   = K + base + (size_t)row * E + hc + cc * 8;
        vga[c]   = VT + vtb + (size_t)(hc + row) * S + cc * 8;
    }

    short8 kr[2], vr[2];
    auto load_regs = [&](int t) {
#pragma unroll
        for (int c = 0; c < 2; ++c) {
            kr[c] = *(const short8*)(kga[c] + (size_t)t * 64 * E);
            vr[c] = *(const short8*)(vga[c] + t * 64);
        }
    };
    auto store_regs = [&](short* Kn, short* Vn) {
#pragma unroll
        for (int c = 0; c < 2; ++c) {
            *(short8*)(&Kn[kdst[c]]) = kr[c];
            short4 lo, hi;
            lo.x = vr[c][0]; lo.y = vr[c][1]; lo.z = vr[c][2]; lo.w = vr[c][3];
            hi.x = vr[c][4]; hi.y = vr[c][5]; hi.z = vr[c][6]; hi.w = vr[c][7];
            *(short4*)(&Vn[vdst0[c]]) = lo;
            *(short4*)(&Vn[vdst1[c]]) = hi;
        }
    };

    const short8 ones = (short8){0x3F80, 0x3F80, 0x3F80, 0x3F80,
                                 0x3F80, 0x3F80, 0x3F80, 0x3F80};
    const float  LB   = 0.00281502f;   // log2(1 + 2^-9): centers P truncation

    uint4v pkvA[2][2], pkvB[2][2];   // [qg][ks] two P-state sets (prev/cur)

    // QK half h (kn = 2h, 2h+1): writes pc[*][h]
    auto qk_half = [&](const short* Kc, uint4v (&pc)[2][2], int h) {
#pragma unroll
        for (int kh = 0; kh < 2; ++kh) {
            const int    kn  = h * 2 + kh;
            const short* kb  = &Kc[(kn * 16 + l16) * 64];
            short8       bk0 = *(const short8*)(kb + ((quad ^ xr) * 8));
            short8       bk1 = *(const short8*)(kb + (((quad + 4) ^ xr) * 8));
#pragma unroll
            for (int qg = 0; qg < 2; ++qg) {
                f32x4 a = (f32x4){LB, LB, LB, LB};
                a = __builtin_amdgcn_mfma_f32_16x16x32_bf16(bk0, aq[qg][0], a, 0, 0, 0);
                a = __builtin_amdgcn_mfma_f32_16x16x32_bf16(bk1, aq[qg][1], a, 0, 0, 0);
                pc[qg][h][kh * 2]     = pack_trunc(EXP2(a[0]), EXP2(a[1]));
                pc[qg][h][kh * 2 + 1] = pack_trunc(EXP2(a[2]), EXP2(a[3]));
            }
        }
    };
    // PV slice ks: consumes pp[*][ks]
    auto pv_half = [&](const short* Vp, uint4v (&pp)[2][2], int ks) {
        short8 pf[2];
#pragma unroll
        for (int qg = 0; qg < 2; ++qg) {
            union { uint4v u; short8 s; } cv;
            cv.u   = pp[qg][ks];
            pf[qg] = cv.s;
            o_sum[qg] = __builtin_amdgcn_mfma_f32_16x16x32_bf16(
                ones, pf[qg], o_sum[qg], 0, 0, 0);
        }
#pragma unroll
        for (int ni = 0; ni < 4; ++ni) {
            const int rv = ni * 16 + l16;
            short8 vb =
                *(const short8*)(&Vp[rv * 64 + (((ks * 4 + quad) ^ xr) * 8)]);
#pragma unroll
            for (int qg = 0; qg < 2; ++qg)
                oT[qg][ni] = __builtin_amdgcn_mfma_f32_16x16x32_bf16(
                    vb, pf[qg], oT[qg][ni], 0, 0, 0);
        }
    };

    // one steady-state iteration: PV(kt-1) interleaved with QK(kt)
    auto body = [&](int kt, uint4v (&pp)[2][2], uint4v (&pc)[2][2]) {
        if (kt + 1 < NT) {
            store_regs(Ks[(kt + 1) & 1], Vs[(kt + 1) % 3]);
            if (kt + 2 < NT) load_regs(kt + 2);
        }
        const short* Kc = Ks[kt & 1];
        const short* Vp = Vs[(kt - 1) % 3];
        __builtin_amdgcn_s_setprio(1);
        pv_half(Vp, pp, 0);
        qk_half(Kc, pc, 0);
        pv_half(Vp, pp, 1);
        qk_half(Kc, pc, 1);
        __builtin_amdgcn_s_setprio(0);
        SOFT_BARRIER();
    };

    // prologue: t0 -> regs -> buf0; t1 -> regs
    load_regs(0);
    store_regs(Ks[0], Vs[0]);
    load_regs(1);
    SOFT_BARRIER();
    // body0: store tile1, prefetch tile2, QK(0) -> pkvA
    store_regs(Ks[1], Vs[1]);
    load_regs(2);
    __builtin_amdgcn_s_setprio(1);
    qk_half(Ks[0], pkvA, 0);
    qk_half(Ks[0], pkvA, 1);
    __builtin_amdgcn_s_setprio(0);
    SOFT_BARRIER();

    // steady state: bodies kt = 1..30 in pairs (static A/B roles), then 31
#pragma unroll 1
    for (int kt = 1; kt < NT - 1; kt += 2) {
        body(kt, pkvA, pkvB);
        body(kt + 1, pkvB, pkvA);
    }
    body(NT - 1, pkvA, pkvB);
    // epilogue PV: tile NT-1 from pkvB, V in Vs[(NT-1)%3]
    __builtin_amdgcn_s_setprio(1);
    pv_half(Vs[(NT - 1) % 3], pkvB, 0);
    pv_half(Vs[(NT - 1) % 3], pkvB, 1);
    __builtin_amdgcn_s_setprio(0);

    // epilogue: O^T C-layout: col=query=l16, row=dim=ni*16+quad*4+r
#pragma unroll
    for (int qg = 0; qg < 2; ++qg) {
        const float inv = 1.0f / o_sum[qg][0];
        const int   qg_ = q0 + qg * 16 + l16;
#pragma unroll
        for (int ni = 0; ni < 4; ++ni) {
            short4 ov;
            ov.x = f2bf(oT[qg][ni][0] * inv);
            ov.y = f2bf(oT[qg][ni][1] * inv);
            ov.z = f2bf(oT[qg][ni][2] * inv);
            ov.w = f2bf(oT[qg][ni][3] * inv);
            *(short4*)(&O[base + (size_t)qg_ * E + hc + ni * 16 + quad * 4]) = ov;
        }
    }
}

// ---------------------------------------------------------------------------
extern "C" void kernel_launch(void* const* d_in, const int* in_sizes, int n_in,
                              void* d_out, int out_size, void* d_ws, size_t ws_size,
                              hipStream_t stream) {
    const float* x  = (const float*)d_in[0];
    const float* Wq = (const float*)d_in[1];
    const float* Wk = (const float*)d_in[2];
    const float* Wv = (const float*)d_in[3];
    const float* Wo = (const float*)d_in[4];
    const float* bo = (const float*)d_in[5];
    float* out = (float*)d_out;

    constexpr int XN = 2 * 2048 * 1024;   // 4M elements
    constexpr int WN = 1024 * 1024;       // 1M elements

    short* Xb  = (short*)d_ws;     // 4M shorts; reused as attention-out buffer
    short* Wqb = Xb + XN;
    short* Wkb = Wqb + WN;
    short* Wvb = Wkb + WN;
    short* Wob = Wvb + WN;
    short* Qb  = Wob + WN;
    short* Kb  = Qb + XN;
    short* VTb = Kb + XN;          // [b][e][s]

    cvt_f32_bf16<<<dim3(8192), 256, 0, stream>>>(
        x, Wq, Wk, Wv, Wo, Xb, Wqb, Wkb, Wvb, Wob);
    proj_gemm<<<dim3(768), 256, 0, stream>>>(Xb, Wqb, Wkb, Wvb, Qb, Kb, VTb);
    attn_kernel<<<dim3(512), 256, 0, stream>>>(Qb, Kb, VTb, Xb /*O*/);
    out_gemm<<<dim3(512), 256, 0, stream>>>(Xb, Wob, bo, out);
}